// Round 1
// baseline (443.412 us; speedup 1.0000x reference)
//
#include <hip/hip_runtime.h>
#include <cstdint>

// SimpleSNN forward: emb-gather -> fc1 -> LIF scan (T=512) -> fc2.
// Output: logits [4,512,32000] f32 + 2 scalar zeros. Spikes stored as
// 64-bit ballot masks; fc2 does b2 + sparse column-sum of W2 (exact).

#define BB 4
#define TT 512
#define DD 512
#define HH 1024
#define VV 32000
#define BT (BB*TT)          // 2048
#define DECAY_F 0.60653066f // exp(-1/2)

// ---------------- fc1: u[bt][h] = dot(emb[ids[bt]], W1[h]) + b1[h] ----------
// tile 64(bt) x 64(h), BK=32, 256 threads, 4x4 micro-tile, K-major LDS.
#define BM 64
#define BN 64
#define BK 32
#define LDSTR 68  // padded row stride (words); keeps float4 16B alignment

__global__ __launch_bounds__(256) void fc1_kernel(
    const int* __restrict__ ids, const float* __restrict__ emb,
    const float* __restrict__ W1, const float* __restrict__ b1,
    float* __restrict__ u)
{
    __shared__ float xs[BK][LDSTR];
    __shared__ float ws[BK][LDSTR];
    __shared__ int s_ids[BM];

    const int tid = threadIdx.x;
    const int bt0 = blockIdx.x * BM;
    const int h0  = blockIdx.y * BN;

    if (tid < BM) s_ids[tid] = ids[bt0 + tid];
    __syncthreads();

    const int row  = tid >> 2;        // 0..63 (tile row for both x and W1)
    const int kseg = (tid & 3) * 8;   // 0,8,16,24

    const int tn = tid & 15;
    const int tm = tid >> 4;
    const int n0 = tn * 4;
    const int m0 = tm * 4;

    float acc[4][4];
    #pragma unroll
    for (int i = 0; i < 4; i++)
        #pragma unroll
        for (int j = 0; j < 4; j++) acc[i][j] = 0.f;

    const long ebase = (long)s_ids[row] * DD;
    const long wbase = (long)(h0 + row) * DD;

    for (int k0 = 0; k0 < DD; k0 += BK) {
        float4 xa = *(const float4*)(emb + ebase + k0 + kseg);
        float4 xb = *(const float4*)(emb + ebase + k0 + kseg + 4);
        float4 wa = *(const float4*)(W1 + wbase + k0 + kseg);
        float4 wb = *(const float4*)(W1 + wbase + k0 + kseg + 4);
        __syncthreads();  // protect previous iteration's LDS reads
        xs[kseg+0][row]=xa.x; xs[kseg+1][row]=xa.y; xs[kseg+2][row]=xa.z; xs[kseg+3][row]=xa.w;
        xs[kseg+4][row]=xb.x; xs[kseg+5][row]=xb.y; xs[kseg+6][row]=xb.z; xs[kseg+7][row]=xb.w;
        ws[kseg+0][row]=wa.x; ws[kseg+1][row]=wa.y; ws[kseg+2][row]=wa.z; ws[kseg+3][row]=wa.w;
        ws[kseg+4][row]=wb.x; ws[kseg+5][row]=wb.y; ws[kseg+6][row]=wb.z; ws[kseg+7][row]=wb.w;
        __syncthreads();
        #pragma unroll
        for (int kk = 0; kk < BK; kk++) {
            float4 xv = *(const float4*)&xs[kk][m0];
            float4 wv = *(const float4*)&ws[kk][n0];
            acc[0][0] += xv.x*wv.x; acc[0][1] += xv.x*wv.y; acc[0][2] += xv.x*wv.z; acc[0][3] += xv.x*wv.w;
            acc[1][0] += xv.y*wv.x; acc[1][1] += xv.y*wv.y; acc[1][2] += xv.y*wv.z; acc[1][3] += xv.y*wv.w;
            acc[2][0] += xv.z*wv.x; acc[2][1] += xv.z*wv.y; acc[2][2] += xv.z*wv.z; acc[2][3] += xv.z*wv.w;
            acc[3][0] += xv.w*wv.x; acc[3][1] += xv.w*wv.y; acc[3][2] += xv.w*wv.z; acc[3][3] += xv.w*wv.w;
        }
    }

    const float4 bv = *(const float4*)(b1 + h0 + n0);
    #pragma unroll
    for (int i = 0; i < 4; i++) {
        float4 o;
        o.x = acc[i][0] + bv.x;
        o.y = acc[i][1] + bv.y;
        o.z = acc[i][2] + bv.z;
        o.w = acc[i][3] + bv.w;
        *(float4*)(u + (long)(bt0 + m0 + i) * HH + h0 + n0) = o;
    }
}

// ---------------- LIF scan over T, one thread per (b,h), ballot -> mask -----
__global__ __launch_bounds__(256) void scan_kernel(
    const float* __restrict__ u, const float* __restrict__ threshold,
    unsigned long long* __restrict__ masks)
{
    const int gtid = blockIdx.x * 256 + threadIdx.x;   // 0..4095
    const int b = gtid >> 10;
    const int h = gtid & 1023;
    const int lane = threadIdx.x & 63;
    const int chunk = h >> 6;                          // 0..15
    const float thr = threshold[h];

    const float* up = u + (long)b * TT * HH + h;
    unsigned long long* mp = masks + (long)b * TT * 16 + chunk;

    float mem = 0.f;
    float cur[8], nxt[8];
    #pragma unroll
    for (int i = 0; i < 8; i++) cur[i] = up[(long)i * HH];

    for (int t = 0; t < TT; t += 8) {
        if (t + 8 < TT) {
            #pragma unroll
            for (int i = 0; i < 8; i++) nxt[i] = up[(long)(t + 8 + i) * HH];
        }
        #pragma unroll
        for (int i = 0; i < 8; i++) {
            float m = mem * DECAY_F + cur[i];
            bool s = (m >= thr);
            unsigned long long bal = __ballot(s);
            if (lane == 0) mp[(long)(t + i) * 16] = bal;
            mem = s ? 0.f : m;
        }
        #pragma unroll
        for (int i = 0; i < 8; i++) cur[i] = nxt[i];
    }
}

// ---------------- fc2: out[r][v] = b2[v] + sum_{h in mask} W2[v][h] ---------
__global__ __launch_bounds__(256) void fc2_kernel(
    const unsigned long long* __restrict__ masks,
    const float* __restrict__ W2, const float* __restrict__ b2,
    float* __restrict__ out)
{
    __shared__ unsigned long long sm[16];
    const int tid = threadIdx.x;
    const int r = blockIdx.y;                 // 0..2047

    if (tid < 16) sm[tid] = masks[(long)r * 16 + tid];
    __syncthreads();

    unsigned long long m_or = 0;
    #pragma unroll
    for (int i = 0; i < 16; i++) m_or |= sm[i];

    const int v0 = (blockIdx.x * 256 + tid) * 4;
    if (v0 < VV) {
        float4 o = *(const float4*)(b2 + v0);
        if (m_or) {  // sparse fallback: add active W2 columns (exact f32)
            for (int i = 0; i < 16; i++) {
                unsigned long long m = sm[i];
                while (m) {
                    int hb = __ffsll((long long)m) - 1;
                    m &= m - 1;
                    const float* w = W2 + (long)v0 * HH + (i * 64 + hb);
                    o.x += w[0];
                    o.y += w[HH];
                    o.z += w[2 * HH];
                    o.w += w[3 * HH];
                }
            }
        }
        __builtin_nontemporal_store(o.x, out + (long)r * VV + v0 + 0);
        __builtin_nontemporal_store(o.y, out + (long)r * VV + v0 + 1);
        __builtin_nontemporal_store(o.z, out + (long)r * VV + v0 + 2);
        __builtin_nontemporal_store(o.w, out + (long)r * VV + v0 + 3);
    }
    if (blockIdx.x == 0 && blockIdx.y == 0 && tid == 0) {
        out[(long)BT * VV + 0] = 0.f;   // avg_spikes
        out[(long)BT * VV + 1] = 0.f;   // mem_out
    }
}

extern "C" void kernel_launch(void* const* d_in, const int* in_sizes, int n_in,
                              void* d_out, int out_size, void* d_ws, size_t ws_size,
                              hipStream_t stream) {
    const int*   ids = (const int*)  d_in[0];
    const float* emb = (const float*)d_in[1];
    const float* W1  = (const float*)d_in[2];
    const float* b1  = (const float*)d_in[3];
    const float* W2  = (const float*)d_in[4];
    const float* b2  = (const float*)d_in[5];
    const float* thr = (const float*)d_in[6];
    float* out = (float*)d_out;

    // workspace: u [B,T,H] f32 (8 MiB) + masks [B*T,16] u64 (256 KiB)
    float* u = (float*)d_ws;
    unsigned long long* masks =
        (unsigned long long*)((char*)d_ws + (size_t)BT * HH * sizeof(float));

    fc1_kernel<<<dim3(BT / BM, HH / BN), 256, 0, stream>>>(ids, emb, W1, b1, u);
    scan_kernel<<<dim3(BB * HH / 256), 256, 0, stream>>>(u, thr, masks);
    fc2_kernel<<<dim3((VV + 1023) / 1024, BT), 256, 0, stream>>>(masks, W2, b2, out);
}